// Round 2
// baseline (3099.301 us; speedup 1.0000x reference)
//
#include <hip/hip_runtime.h>

// 2-layer LSTM (H=50) + final linear head, fused into one persistent-loop kernel.
// B=4096, T=512, D=2. fp32 throughout (no fp32 MFMA on CDNA4 -> vector VALU bound).
//
// Mapping: 512 blocks x 256 threads. Each block owns R=8 batch rows.
//  - Matvec phases: thread tid<200 owns gate-unit gu (gate g = gu/50, unit u = gu%50);
//    its weight rows W_hh0[gu,:], W_ih1[gu,:], W_hh1[gu,:] live in VGPRs (3*52 regs).
//    h-state is read from LDS with all-lane-broadcast float4 reads (conflict-free).
//  - Elementwise phases: thread tid<200 -> (u = tid%50, rr = tid/50) handles batches
//    rr and rr+4; cell state c kept in registers.
//  - x slice (8 batches x 512 steps x 2) staged to LDS once: no global loads in loop.
// 3 barriers per timestep (separate gate buffers per layer remove the 4th).

#define Hh   50
#define HP   52          // padded to multiple of 4 for float4 reads
#define G4   200         // 4*H
#define TT   512
#define DD   2
#define RR   8           // batches per block
#define BLK  256

__device__ __forceinline__ float fast_rcp(float x) { return __builtin_amdgcn_rcpf(x); }
__device__ __forceinline__ float sigm(float x) {
    return fast_rcp(1.0f + __expf(-x));
}
__device__ __forceinline__ float tanh_fast(float x) {
    // tanh(x) = 1 - 2/(e^{2x}+1); exp overflow -> inf -> rcp -> 0 -> +1 (correct limit)
    return 1.0f - 2.0f * fast_rcp(__expf(2.0f * x) + 1.0f);
}

extern "C" __global__ void __launch_bounds__(BLK, 2)
lstm2_fused(const float* __restrict__ x,
            const float* __restrict__ W_ih0, const float* __restrict__ W_hh0,
            const float* __restrict__ b0,
            const float* __restrict__ W_ih1, const float* __restrict__ W_hh1,
            const float* __restrict__ b1,
            const float* __restrict__ W_fc,  const float* __restrict__ b_fc,
            float* __restrict__ out)
{
    __shared__ float xall[RR][TT][DD];     // 32768 B, constant after init
    __shared__ float h0s[RR][HP];          // layer0 hidden state (pad [50..51] = 0)
    __shared__ float h1s[RR][HP];          // layer1 hidden state
    __shared__ float gates0[RR][G4];       // layer0 gate preactivations
    __shared__ float gates1[RR][G4];       // layer1 gate preactivations

    const int tid   = threadIdx.x;
    const int bbase = blockIdx.x * RR;

    // ---- stage x slice for this block's 8 batches (coalesced float4) ----
    {
        const float4* src = reinterpret_cast<const float4*>(x + (size_t)bbase * TT * DD);
        float4* dst = reinterpret_cast<float4*>(&xall[0][0][0]);
        const int n4 = RR * TT * DD / 4;   // 2048
        for (int i = tid; i < n4; i += BLK) dst[i] = src[i];
    }
    // ---- zero hidden state (incl. padding, so pad*weightpad = 0 always) ----
    for (int i = tid; i < RR * HP; i += BLK) {
        (&h0s[0][0])[i] = 0.0f;
        (&h1s[0][0])[i] = 0.0f;
    }

    // ---- per-thread weights in registers ----
    const int gu = (tid < G4) ? tid : 0;   // idle threads alias gu=0 (loads unused)
    const float wi0_0 = W_ih0[gu * 2 + 0];
    const float wi0_1 = W_ih0[gu * 2 + 1];
    const float bias0 = b0[gu];
    const float bias1 = b1[gu];
    float whh0r[HP], wih1r[HP], whh1r[HP];
#pragma unroll
    for (int k = 0; k < Hh; ++k) {
        whh0r[k] = W_hh0[gu * Hh + k];
        wih1r[k] = W_ih1[gu * Hh + k];
        whh1r[k] = W_hh1[gu * Hh + k];
    }
#pragma unroll
    for (int k = Hh; k < HP; ++k) { whh0r[k] = 0.0f; wih1r[k] = 0.0f; whh1r[k] = 0.0f; }

    // ---- elementwise-phase identity: (u, rr) -> batches rr and rr+4 ----
    const int eu = (tid < G4) ? (tid % Hh) : 0;
    const int er = (tid < G4) ? (tid / Hh) : 0;      // 0..3
    float c0a = 0.0f, c0b = 0.0f, c1a = 0.0f, c1b = 0.0f;

    __syncthreads();

    for (int t = 0; t < TT; ++t) {
        // ================= phase A: layer0 gate preactivations =================
        if (tid < G4) {
            float acc[RR];
#pragma unroll
            for (int r = 0; r < RR; ++r) {
                const float2 xv = *reinterpret_cast<const float2*>(&xall[r][t][0]);
                acc[r] = fmaf(wi0_0, xv.x, fmaf(wi0_1, xv.y, bias0));
            }
#pragma unroll
            for (int k4 = 0; k4 < HP / 4; ++k4) {
#pragma unroll
                for (int r = 0; r < RR; ++r) {
                    const float4 h = *reinterpret_cast<const float4*>(&h0s[r][k4 * 4]);
                    acc[r] = fmaf(whh0r[4 * k4 + 0], h.x, acc[r]);
                    acc[r] = fmaf(whh0r[4 * k4 + 1], h.y, acc[r]);
                    acc[r] = fmaf(whh0r[4 * k4 + 2], h.z, acc[r]);
                    acc[r] = fmaf(whh0r[4 * k4 + 3], h.w, acc[r]);
                }
            }
#pragma unroll
            for (int r = 0; r < RR; ++r) gates0[r][gu] = acc[r];
        }
        __syncthreads();

        // ================= phase B: layer0 elementwise ==========================
        if (tid < G4) {
            {
                const int r = er;
                const float ig = sigm(gates0[r][eu]);
                const float fg = sigm(gates0[r][Hh + eu]);
                const float gg = tanh_fast(gates0[r][2 * Hh + eu]);
                const float og = sigm(gates0[r][3 * Hh + eu]);
                c0a = fmaf(fg, c0a, ig * gg);
                h0s[r][eu] = og * tanh_fast(c0a);
            }
            {
                const int r = er + 4;
                const float ig = sigm(gates0[r][eu]);
                const float fg = sigm(gates0[r][Hh + eu]);
                const float gg = tanh_fast(gates0[r][2 * Hh + eu]);
                const float og = sigm(gates0[r][3 * Hh + eu]);
                c0b = fmaf(fg, c0b, ig * gg);
                h0s[r][eu] = og * tanh_fast(c0b);
            }
        }
        __syncthreads();

        // ================= phase C: layer1 gate preactivations =================
        if (tid < G4) {
            float acc[RR];
#pragma unroll
            for (int r = 0; r < RR; ++r) acc[r] = bias1;
#pragma unroll
            for (int k4 = 0; k4 < HP / 4; ++k4) {
#pragma unroll
                for (int r = 0; r < RR; ++r) {
                    const float4 ha = *reinterpret_cast<const float4*>(&h0s[r][k4 * 4]);
                    const float4 hb = *reinterpret_cast<const float4*>(&h1s[r][k4 * 4]);
                    acc[r] = fmaf(wih1r[4 * k4 + 0], ha.x, acc[r]);
                    acc[r] = fmaf(wih1r[4 * k4 + 1], ha.y, acc[r]);
                    acc[r] = fmaf(wih1r[4 * k4 + 2], ha.z, acc[r]);
                    acc[r] = fmaf(wih1r[4 * k4 + 3], ha.w, acc[r]);
                    acc[r] = fmaf(whh1r[4 * k4 + 0], hb.x, acc[r]);
                    acc[r] = fmaf(whh1r[4 * k4 + 1], hb.y, acc[r]);
                    acc[r] = fmaf(whh1r[4 * k4 + 2], hb.z, acc[r]);
                    acc[r] = fmaf(whh1r[4 * k4 + 3], hb.w, acc[r]);
                }
            }
#pragma unroll
            for (int r = 0; r < RR; ++r) gates1[r][gu] = acc[r];
        }
        __syncthreads();

        // ================= phase D: layer1 elementwise ==========================
        if (tid < G4) {
            {
                const int r = er;
                const float ig = sigm(gates1[r][eu]);
                const float fg = sigm(gates1[r][Hh + eu]);
                const float gg = tanh_fast(gates1[r][2 * Hh + eu]);
                const float og = sigm(gates1[r][3 * Hh + eu]);
                c1a = fmaf(fg, c1a, ig * gg);
                h1s[r][eu] = og * tanh_fast(c1a);
            }
            {
                const int r = er + 4;
                const float ig = sigm(gates1[r][eu]);
                const float fg = sigm(gates1[r][Hh + eu]);
                const float gg = tanh_fast(gates1[r][2 * Hh + eu]);
                const float og = sigm(gates1[r][3 * Hh + eu]);
                c1b = fmaf(fg, c1b, ig * gg);
                h1s[r][eu] = og * tanh_fast(c1b);
            }
        }
        __syncthreads();
        // no 4th barrier needed: next phase A touches only gates0/h0s/xall,
        // which are separated from phase D's gates1/h1s by the two barriers above.
    }

    // ================= final linear head on h1(T-1) =================
    if (tid < RR) {
        float dot = b_fc[0];
#pragma unroll
        for (int u = 0; u < Hh; ++u) dot = fmaf(W_fc[u], h1s[tid][u], dot);
        out[bbase + tid] = dot;
    }
}

extern "C" void kernel_launch(void* const* d_in, const int* in_sizes, int n_in,
                              void* d_out, int out_size, void* d_ws, size_t ws_size,
                              hipStream_t stream) {
    const float* x     = (const float*)d_in[0];
    const float* W_ih0 = (const float*)d_in[1];
    const float* W_hh0 = (const float*)d_in[2];
    const float* b0    = (const float*)d_in[3];
    const float* W_ih1 = (const float*)d_in[4];
    const float* W_hh1 = (const float*)d_in[5];
    const float* b1    = (const float*)d_in[6];
    const float* W_fc  = (const float*)d_in[7];
    const float* b_fc  = (const float*)d_in[8];
    float* out = (float*)d_out;

    const int B = in_sizes[0] / (TT * DD);   // 4096
    dim3 grid(B / RR), block(BLK);
    hipLaunchKernelGGL(lstm2_fused, grid, block, 0, stream,
                       x, W_ih0, W_hh0, b0, W_ih1, W_hh1, b1, W_fc, b_fc, out);
}

// Round 3
// 2992.620 us; speedup vs baseline: 1.0356x; 1.0356x over previous
//
#include <hip/hip_runtime.h>

// 2-layer LSTM (H=50) + linear head. Layer-pipelined 2-gang kernel.
//
// Block = 512 threads = 8 waves. Gang0 = waves 0..3 (layer 0), gang1 = waves
// 4..7 (layer 1, lagging one timestep). Each gang's thread lt<200 owns one
// gate-unit row:
//   gang0: W_hh0[gu,:] in wreg[0..51] (pad=0) + 2 x-weights + bias   (~57 regs)
//   gang1: [W_ih1[gu,:] | W_hh1[gu,:]] in wreg[0..103] (pads=0)      (~105 regs)
// wreg is a single unioned array so block VGPR = max path (~120 < 128 cap).
// h-state lives in LDS as hcat[r] = [h0 (0..49) | pad | h1 (52..101) | pad];
// matvec reads are all-lane-broadcast float4 (conflict-free).
// Pipeline per step s: gang0 makes h0[s] (s<T), gang1 makes h1[s-1] (s>=1);
// exactly 2 barriers/step, single-buffered hcat (phase separation proves safety).
// Cell states stay in elementwise threads' registers.

#define Hh   50
#define G4   200
#define TT   512
#define DD   2
#define RR   8      // batches per block
#define BLK  512
#define HC   104    // hcat row: h0[0..49], pad[50..51], h1[52..101], pad[102..103]
#define H1   52     // h1 offset within hcat row

__device__ __forceinline__ float fast_rcp(float x) { return __builtin_amdgcn_rcpf(x); }
__device__ __forceinline__ float sigm(float x) { return fast_rcp(1.0f + __expf(-x)); }
__device__ __forceinline__ float tanh_fast(float x) {
    // tanh(x) = 1 - 2/(e^{2x}+1); overflow -> inf -> rcp -> 0 -> 1 (correct limit)
    return 1.0f - 2.0f * fast_rcp(__expf(2.0f * x) + 1.0f);
}

extern "C" __global__ void __launch_bounds__(BLK, 4)
lstm2_pipe(const float* __restrict__ x,
           const float* __restrict__ W_ih0, const float* __restrict__ W_hh0,
           const float* __restrict__ b0,
           const float* __restrict__ W_ih1, const float* __restrict__ W_hh1,
           const float* __restrict__ b1,
           const float* __restrict__ W_fc,  const float* __restrict__ b_fc,
           float* __restrict__ out)
{
    __shared__ float xall[RR][TT][DD];   // 32 KB, read-only after staging
    __shared__ float hcat[RR][HC];       // 3.3 KB, pads stay 0 forever
    __shared__ float gat0[RR][G4];       // layer0 gate preactivations
    __shared__ float gat1[RR][G4];       // layer1 gate preactivations

    const int  tid   = threadIdx.x;
    const bool is_g1 = (tid >= 256);     // wave-uniform (256 = 4 waves)
    const int  lt    = is_g1 ? tid - 256 : tid;
    const bool act   = (lt < G4);
    const int  gu    = act ? lt : 0;
    const int  bbase = blockIdx.x * RR;

    // ---- stage x slice (coalesced float4, 4 iters exactly) ----
    {
        const float4* src = reinterpret_cast<const float4*>(x + (size_t)bbase * TT * DD);
        float4* dst = reinterpret_cast<float4*>(&xall[0][0][0]);
#pragma unroll
        for (int i = 0; i < (RR * TT * DD / 4) / BLK; ++i)
            dst[tid + i * BLK] = src[tid + i * BLK];
    }
    // ---- zero hcat (incl. pads: pad * zero-weight contributes 0 forever) ----
    for (int i = tid; i < RR * HC; i += BLK) (&hcat[0][0])[i] = 0.0f;

    // ---- per-thread weights: unioned register array ----
    float wreg[HC];
    float wx0 = 0.0f, wx1 = 0.0f, bias;
    if (!is_g1) {
        wx0  = W_ih0[gu * DD + 0];
        wx1  = W_ih0[gu * DD + 1];
        bias = b0[gu];
#pragma unroll
        for (int k = 0; k < Hh; ++k) wreg[k] = W_hh0[gu * Hh + k];
#pragma unroll
        for (int k = Hh; k < H1; ++k) wreg[k] = 0.0f;
        // wreg[52..103] unused on this path (never read)
    } else {
        bias = b1[gu];
#pragma unroll
        for (int k = 0; k < Hh; ++k) wreg[k] = W_ih1[gu * Hh + k];
#pragma unroll
        for (int k = Hh; k < H1; ++k) wreg[k] = 0.0f;
#pragma unroll
        for (int k = 0; k < Hh; ++k) wreg[H1 + k] = W_hh1[gu * Hh + k];
#pragma unroll
        for (int k = H1 + Hh; k < HC; ++k) wreg[k] = 0.0f;
    }

    // ---- elementwise identity: (u, er) -> batches er and er+4 ----
    const int eu = act ? (lt % Hh) : 0;
    const int er = act ? (lt / Hh) : 0;     // 0..3
    float c_a = 0.0f, c_b = 0.0f;           // cell state (layer 0 or 1 per gang)

    __syncthreads();

    for (int s = 0; s <= TT; ++s) {
        // ============ phase 1: matvecs (both gangs concurrently) ============
        if (!is_g1) {
            if (s < TT && act) {
#pragma unroll
                for (int half = 0; half < 2; ++half) {
                    float acc[4];
#pragma unroll
                    for (int q = 0; q < 4; ++q) {
                        const int r = half * 4 + q;
                        const float2 xv = *reinterpret_cast<const float2*>(&xall[r][s][0]);
                        acc[q] = fmaf(wx0, xv.x, fmaf(wx1, xv.y, bias));
                    }
#pragma unroll
                    for (int k4 = 0; k4 < 13; ++k4) {
#pragma unroll
                        for (int q = 0; q < 4; ++q) {
                            const int r = half * 4 + q;
                            const float4 h = *reinterpret_cast<const float4*>(&hcat[r][k4 * 4]);
                            acc[q] = fmaf(wreg[4 * k4 + 0], h.x, acc[q]);
                            acc[q] = fmaf(wreg[4 * k4 + 1], h.y, acc[q]);
                            acc[q] = fmaf(wreg[4 * k4 + 2], h.z, acc[q]);
                            acc[q] = fmaf(wreg[4 * k4 + 3], h.w, acc[q]);
                        }
                    }
#pragma unroll
                    for (int q = 0; q < 4; ++q) gat0[half * 4 + q][gu] = acc[q];
                }
            }
        } else {
            if (s >= 1 && act) {
#pragma unroll
                for (int half = 0; half < 2; ++half) {
                    float acc[4];
#pragma unroll
                    for (int q = 0; q < 4; ++q) acc[q] = bias;
#pragma unroll
                    for (int k4 = 0; k4 < HC / 4; ++k4) {   // 26: h0 then h1, one dot
#pragma unroll
                        for (int q = 0; q < 4; ++q) {
                            const int r = half * 4 + q;
                            const float4 h = *reinterpret_cast<const float4*>(&hcat[r][k4 * 4]);
                            acc[q] = fmaf(wreg[4 * k4 + 0], h.x, acc[q]);
                            acc[q] = fmaf(wreg[4 * k4 + 1], h.y, acc[q]);
                            acc[q] = fmaf(wreg[4 * k4 + 2], h.z, acc[q]);
                            acc[q] = fmaf(wreg[4 * k4 + 3], h.w, acc[q]);
                        }
                    }
#pragma unroll
                    for (int q = 0; q < 4; ++q) gat1[half * 4 + q][gu] = acc[q];
                }
            }
        }
        __syncthreads();

        // ============ phase 2: elementwise (both gangs concurrently) ============
        if (!is_g1) {
            if (s < TT && act) {
                {
                    const int r = er;
                    const float ig = sigm(gat0[r][eu]);
                    const float fg = sigm(gat0[r][Hh + eu]);
                    const float gg = tanh_fast(gat0[r][2 * Hh + eu]);
                    const float og = sigm(gat0[r][3 * Hh + eu]);
                    c_a = fmaf(fg, c_a, ig * gg);
                    hcat[r][eu] = og * tanh_fast(c_a);
                }
                {
                    const int r = er + 4;
                    const float ig = sigm(gat0[r][eu]);
                    const float fg = sigm(gat0[r][Hh + eu]);
                    const float gg = tanh_fast(gat0[r][2 * Hh + eu]);
                    const float og = sigm(gat0[r][3 * Hh + eu]);
                    c_b = fmaf(fg, c_b, ig * gg);
                    hcat[r][eu] = og * tanh_fast(c_b);
                }
            }
        } else {
            if (s >= 1 && act) {
                {
                    const int r = er;
                    const float ig = sigm(gat1[r][eu]);
                    const float fg = sigm(gat1[r][Hh + eu]);
                    const float gg = tanh_fast(gat1[r][2 * Hh + eu]);
                    const float og = sigm(gat1[r][3 * Hh + eu]);
                    c_a = fmaf(fg, c_a, ig * gg);
                    hcat[r][H1 + eu] = og * tanh_fast(c_a);
                }
                {
                    const int r = er + 4;
                    const float ig = sigm(gat1[r][eu]);
                    const float fg = sigm(gat1[r][Hh + eu]);
                    const float gg = tanh_fast(gat1[r][2 * Hh + eu]);
                    const float og = sigm(gat1[r][3 * Hh + eu]);
                    c_b = fmaf(fg, c_b, ig * gg);
                    hcat[r][H1 + eu] = og * tanh_fast(c_b);
                }
            }
        }
        __syncthreads();
    }

    // ---- final linear head on h1[T-1] (last barrier above guarantees vis) ----
    if (tid < RR) {
        float dot = b_fc[0];
#pragma unroll
        for (int u = 0; u < Hh; ++u) dot = fmaf(W_fc[u], hcat[tid][H1 + u], dot);
        out[bbase + tid] = dot;
    }
}

extern "C" void kernel_launch(void* const* d_in, const int* in_sizes, int n_in,
                              void* d_out, int out_size, void* d_ws, size_t ws_size,
                              hipStream_t stream) {
    const float* x     = (const float*)d_in[0];
    const float* W_ih0 = (const float*)d_in[1];
    const float* W_hh0 = (const float*)d_in[2];
    const float* b0    = (const float*)d_in[3];
    const float* W_ih1 = (const float*)d_in[4];
    const float* W_hh1 = (const float*)d_in[5];
    const float* b1    = (const float*)d_in[6];
    const float* W_fc  = (const float*)d_in[7];
    const float* b_fc  = (const float*)d_in[8];
    float* out = (float*)d_out;

    const int B = in_sizes[0] / (TT * DD);   // 4096
    dim3 grid(B / RR), block(BLK);
    hipLaunchKernelGGL(lstm2_pipe, grid, block, 0, stream,
                       x, W_ih0, W_hh0, b0, W_ih1, W_hh1, b1, W_fc, b_fc, out);
}

// Round 4
// 2888.127 us; speedup vs baseline: 1.0731x; 1.0362x over previous
//
#include <hip/hip_runtime.h>

// 2-layer LSTM (H=50) + linear head. Three-gang split so per-thread weight
// arrays are only 52 floats (register-resident, no spills).
//
// Block = 768 threads = 12 waves, RR = 8 batches/block, grid = 512 blocks
// (exactly 2 blocks/CU on 256 CUs). __launch_bounds__(768,6): 6 waves/SIMD.
//   gang0 (tid 0..255):   L0 gates  = W_hh0[gu,:]·h0 + W_ih0[gu,:]·x + b0
//   gang1 (tid 256..511): L1 part B = W_ih1[gu,:]·h0 + b1
//   gang2 (tid 512..767): L1 part C = W_hh1[gu,:]·h1
// All three run ONE code path (identical FMA loop, gang-selected base ptrs).
// Layer 1 lags layer 0 by one step (round-2 pipeline). 2 barriers/step.
// h state: hcat[r] = [h0(0..49)|pad|h1(52..101)|pad]; broadcast float4 reads.
// Cell states in registers of the elementwise threads (gang0=c0, gang1=c1).

#define Hh   50
#define G4   200
#define TT   512
#define DD   2
#define RR   8
#define BLK  768
#define HC   104    // hcat row: h0[0..49],pad,pad,h1[52..101],pad,pad
#define H1o  52

__device__ __forceinline__ float fast_rcp(float x) { return __builtin_amdgcn_rcpf(x); }
__device__ __forceinline__ float sigm(float x) { return fast_rcp(1.0f + __expf(-x)); }
__device__ __forceinline__ float tanh_fast(float x) {
    // tanh(x) = 1 - 2/(e^{2x}+1); overflow -> inf -> rcp -> 0 -> 1 (correct limit)
    return 1.0f - 2.0f * fast_rcp(__expf(2.0f * x) + 1.0f);
}

extern "C" __global__ void __launch_bounds__(BLK, 6)
lstm2_g3(const float* __restrict__ x,
         const float* __restrict__ W_ih0, const float* __restrict__ W_hh0,
         const float* __restrict__ b0,
         const float* __restrict__ W_ih1, const float* __restrict__ W_hh1,
         const float* __restrict__ b1,
         const float* __restrict__ W_fc,  const float* __restrict__ b_fc,
         float* __restrict__ out)
{
    __shared__ float xall[RR][TT][DD];   // 32 KB
    __shared__ float hcat[RR][HC];       // 3.3 KB (pads stay 0)
    __shared__ float gat0[RR][G4];       // L0 preactivations
    __shared__ float gatB[RR][G4];       // L1 partial (W_ih1 · h0 + b1)
    __shared__ float gatC[RR][G4];       // L1 partial (W_hh1 · h1)

    const int  tid  = threadIdx.x;
    const int  gang = tid >> 8;          // 0,1,2 — wave-uniform
    const int  lt   = tid & 255;
    const bool act  = (lt < G4);
    const int  gu   = act ? lt : 0;
    const int  bbase = blockIdx.x * RR;

    // ---- stage x slice (coalesced float4) ----
    {
        const float4* src = reinterpret_cast<const float4*>(x + (size_t)bbase * TT * DD);
        float4* dst = reinterpret_cast<float4*>(&xall[0][0][0]);
        for (int i = tid; i < RR * TT * DD / 4; i += BLK) dst[i] = src[i];
    }
    // ---- zero hcat (incl. pads: pad * 0-weight = 0 forever) ----
    for (int i = tid; i < RR * HC; i += BLK) (&hcat[0][0])[i] = 0.0f;

    // ---- per-thread weights: 52 floats, single code shape for all gangs ----
    const float* wsrc = (gang == 0) ? W_hh0 : (gang == 1) ? W_ih1 : W_hh1;
    float w[H1o];
#pragma unroll
    for (int k = 0; k < Hh; ++k) w[k] = wsrc[gu * Hh + k];
    w[50] = 0.0f; w[51] = 0.0f;
    float wx0 = 0.0f, wx1 = 0.0f, bias = 0.0f;
    if (gang == 0) { wx0 = W_ih0[gu * DD]; wx1 = W_ih0[gu * DD + 1]; bias = b0[gu]; }
    else if (gang == 1) { bias = b1[gu]; }

    // gang-selected bases (loop-invariant, in registers)
    const float4* h4   = reinterpret_cast<const float4*>(&hcat[0][0]) + (gang == 2 ? H1o / 4 : 0);
    float*        gout = (gang == 0) ? &gat0[0][0] : (gang == 1) ? &gatB[0][0] : &gatC[0][0];
    const int s_lo = (gang == 0) ? 0 : 1;           // L1 lags one step
    const int s_hi = (gang == 0) ? TT : TT + 1;

    // elementwise identity: (u, er) -> batches er and er+4
    const int eu = act ? (lt % Hh) : 0;
    const int er = act ? (lt / Hh) : 0;
    float c_a = 0.0f, c_b = 0.0f;   // gang0: layer-0 cell; gang1: layer-1 cell

    __syncthreads();

    for (int s = 0; s <= TT; ++s) {
        // ================= phase 1: all three matvecs concurrently =================
        if (act && s >= s_lo && s < s_hi) {
            const int sx = (s < TT) ? s : 0;   // clamp (gangs 1,2 at s=TT; wx=0 anyway)
#pragma unroll
            for (int half = 0; half < 2; ++half) {
                float acc[4];
#pragma unroll
                for (int q = 0; q < 4; ++q) {
                    const int r = half * 4 + q;
                    const float2 xv = *reinterpret_cast<const float2*>(&xall[r][sx][0]);
                    acc[q] = fmaf(wx0, xv.x, fmaf(wx1, xv.y, bias));
                }
#pragma unroll
                for (int k4 = 0; k4 < 13; ++k4) {
#pragma unroll
                    for (int q = 0; q < 4; ++q) {
                        const float4 h = h4[(half * 4 + q) * (HC / 4) + k4];
                        acc[q] = fmaf(w[4 * k4 + 0], h.x, acc[q]);
                        acc[q] = fmaf(w[4 * k4 + 1], h.y, acc[q]);
                        acc[q] = fmaf(w[4 * k4 + 2], h.z, acc[q]);
                        acc[q] = fmaf(w[4 * k4 + 3], h.w, acc[q]);
                    }
                }
#pragma unroll
                for (int q = 0; q < 4; ++q) gout[(half * 4 + q) * G4 + gu] = acc[q];
            }
        }
        __syncthreads();

        // ================= phase 2: elementwise =================
        if (gang == 0) {
            if (act && s < TT) {
                {
                    const int r = er;
                    const float ig = sigm(gat0[r][eu]);
                    const float fg = sigm(gat0[r][Hh + eu]);
                    const float gg = tanh_fast(gat0[r][2 * Hh + eu]);
                    const float og = sigm(gat0[r][3 * Hh + eu]);
                    c_a = fmaf(fg, c_a, ig * gg);
                    hcat[r][eu] = og * tanh_fast(c_a);
                }
                {
                    const int r = er + 4;
                    const float ig = sigm(gat0[r][eu]);
                    const float fg = sigm(gat0[r][Hh + eu]);
                    const float gg = tanh_fast(gat0[r][2 * Hh + eu]);
                    const float og = sigm(gat0[r][3 * Hh + eu]);
                    c_b = fmaf(fg, c_b, ig * gg);
                    hcat[r][eu] = og * tanh_fast(c_b);
                }
            }
        } else if (gang == 1) {
            if (act && s >= 1) {
                {
                    const int r = er;
                    const float ig = sigm(gatB[r][eu]           + gatC[r][eu]);
                    const float fg = sigm(gatB[r][Hh + eu]      + gatC[r][Hh + eu]);
                    const float gg = tanh_fast(gatB[r][2 * Hh + eu] + gatC[r][2 * Hh + eu]);
                    const float og = sigm(gatB[r][3 * Hh + eu]  + gatC[r][3 * Hh + eu]);
                    c_a = fmaf(fg, c_a, ig * gg);
                    hcat[r][H1o + eu] = og * tanh_fast(c_a);
                }
                {
                    const int r = er + 4;
                    const float ig = sigm(gatB[r][eu]           + gatC[r][eu]);
                    const float fg = sigm(gatB[r][Hh + eu]      + gatC[r][Hh + eu]);
                    const float gg = tanh_fast(gatB[r][2 * Hh + eu] + gatC[r][2 * Hh + eu]);
                    const float og = sigm(gatB[r][3 * Hh + eu]  + gatC[r][3 * Hh + eu]);
                    c_b = fmaf(fg, c_b, ig * gg);
                    hcat[r][H1o + eu] = og * tanh_fast(c_b);
                }
            }
        }
        // gang2 idle in phase 2 (short phase; acceptable)
        __syncthreads();
    }

    // ---- final linear head on h1[T-1] ----
    if (tid < RR) {
        float dot = b_fc[0];
#pragma unroll
        for (int u = 0; u < Hh; ++u) dot = fmaf(W_fc[u], hcat[tid][H1o + u], dot);
        out[bbase + tid] = dot;
    }
}

extern "C" void kernel_launch(void* const* d_in, const int* in_sizes, int n_in,
                              void* d_out, int out_size, void* d_ws, size_t ws_size,
                              hipStream_t stream) {
    const float* x     = (const float*)d_in[0];
    const float* W_ih0 = (const float*)d_in[1];
    const float* W_hh0 = (const float*)d_in[2];
    const float* b0    = (const float*)d_in[3];
    const float* W_ih1 = (const float*)d_in[4];
    const float* W_hh1 = (const float*)d_in[5];
    const float* b1    = (const float*)d_in[6];
    const float* W_fc  = (const float*)d_in[7];
    const float* b_fc  = (const float*)d_in[8];
    float* out = (float*)d_out;

    const int B = in_sizes[0] / (TT * DD);   // 4096
    dim3 grid(B / RR), block(BLK);
    hipLaunchKernelGGL(lstm2_g3, grid, block, 0, stream,
                       x, W_ih0, W_hh0, b0, W_ih1, W_hh1, b1, W_fc, b_fc, out);
}

// Round 5
// 1945.626 us; speedup vs baseline: 1.5930x; 1.4844x over previous
//
#include <hip/hip_runtime.h>

// 2-layer LSTM (H=50) + linear head — MFMA rewrite.
//
// Why: rounds 2-4 all hit ~3.0-3.1 ms because each FMA streamed a 4B h-value
// from LDS (broadcast ds_read returns 16B/lane regardless of address
// identity). LDS return BW = 128 B/cy/CU caps that design at 32 MAC/cy/CU
// = 3.2 ms. MFMA reads fragments once per step and reuses them across tiles.
//
// Structure: block = 256 thr (4 waves) owns 16 batches; grid = 256 (1/CU).
//   wave0: L0 units  0..31   wave1: L0 units 32..49(+pad)
//   wave2: L1 units  0..31   wave3: L1 units 32..49(+pad)   (L1 lags 1 step)
// Gates padded 50->64 per gate type so unit u's 4 gates (i,f,g,o) sit in the
// SAME lane across 4 N-tiles -> elementwise is lane-local.
// K layout (hcat row per batch, f16): [h0 0..49 | x 50,51 | 1.0 @52 | 0.. |
// h1 64..113 | 0..127]  -> bias + x-projection folded into the MFMA K-dim.
// L0: K=64 (2 mfma/tile), L1: K=128 (4 mfma/tile); 8 N-tiles per wave.
// Weights = static B-fragments in registers. One __syncthreads per step,
// double-buffered hcat. Cell state fp32 in registers. Head reads fp32 h1.

typedef _Float16 f16;
typedef f16  f16x8 __attribute__((ext_vector_type(8)));
typedef float f32x4 __attribute__((ext_vector_type(4)));
typedef unsigned short u16;
typedef unsigned int   u32;

#define TT   512
#define MB   16     // batches per block
#define KP   136    // hcat row length in f16 units (128 + 8 pad: bank spread)
#define BLK  256

__device__ __forceinline__ float sigm(float x) {
    return __builtin_amdgcn_rcpf(1.0f + __expf(-x));
}
__device__ __forceinline__ float tanh_(float x) {
    // 1 - 2/(e^{2x}+1); overflow -> inf -> rcp -> 0 -> 1 (correct limit)
    return 1.0f - 2.0f * __builtin_amdgcn_rcpf(__expf(2.0f * x) + 1.0f);
}

// Weight element for B-fragment position (layer, gate g, out-unit u, k).
__device__ __forceinline__ float welem(int layer, int g, int u, int k,
        const float* __restrict__ Wih0, const float* __restrict__ Whh0,
        const float* __restrict__ b0,
        const float* __restrict__ Wih1, const float* __restrict__ Whh1,
        const float* __restrict__ b1) {
    if (u >= 50) return 0.0f;
    const int row = g * 50 + u;           // PyTorch gate order i,f,g,o
    if (layer == 0) {
        if (k < 50)  return Whh0[row * 50 + k];
        if (k < 52)  return Wih0[row * 2 + (k - 50)];
        if (k == 52) return b0[row];
        return 0.0f;
    } else {
        if (k < 50)            return Wih1[row * 50 + k];
        if (k == 52)           return b1[row];
        if (k >= 64 && k < 114) return Whh1[row * 50 + (k - 64)];
        return 0.0f;
    }
}

extern "C" __global__ void __launch_bounds__(BLK, 1)
lstm2_mfma(const float* __restrict__ x,
           const float* __restrict__ W_ih0, const float* __restrict__ W_hh0,
           const float* __restrict__ b0,
           const float* __restrict__ W_ih1, const float* __restrict__ W_hh1,
           const float* __restrict__ b1,
           const float* __restrict__ W_fc,  const float* __restrict__ b_fc,
           float* __restrict__ out)
{
    __shared__ __align__(16) u16 hc[2][MB][KP];   // 8704 B, double-buffered state
    __shared__ u32  xpack[MB][TT];                // 32 KB, x as packed f16 pairs
    __shared__ float hfin[MB][52];                // final h1 in fp32 for the head

    const int tid   = threadIdx.x;
    const int lane  = tid & 63;
    const int wid   = tid >> 6;        // 0..3
    const int layer = wid >> 1;        // 0: L0 waves, 1: L1 waves
    const int ubB   = (wid & 1) * 2;   // unit-block base (x16 units)
    const int col   = lane & 15;       // MFMA low-lane index (A-row / B-col / D-col)
    const int kg    = lane >> 4;       // k-octet / D-row group
    const int bbase = blockIdx.x * MB;

    // ---- stage x -> packed f16 pairs in LDS (coalesced float2 loads) ----
    for (int idx = tid; idx < MB * TT; idx += BLK) {
        const int b = idx >> 9, t = idx & (TT - 1);
        const float2 v = *reinterpret_cast<const float2*>(
            x + ((size_t)(bbase + b) * TT + t) * 2);
        const u16 lo = __builtin_bit_cast(u16, (f16)v.x);
        const u16 hi = __builtin_bit_cast(u16, (f16)v.y);
        xpack[b][t] = (u32)lo | ((u32)hi << 16);
    }
    // ---- zero hcat (both buffers; pads stay 0 forever) ----
    {
        u32* hcU = reinterpret_cast<u32*>(&hc[0][0][0]);
        for (int i = tid; i < 2 * MB * KP / 2; i += BLK) hcU[i] = 0;
    }
    __syncthreads();
    // bias slot (k=52) = 1.0 in both buffers; x[0] into buffer 0
    if (tid < 32) hc[tid >> 4][tid & 15][52] = (u16)0x3C00;  // f16 1.0
    else if (tid >= 32 && tid < 48)
        *reinterpret_cast<u32*>(&hc[0][tid - 32][50]) = xpack[tid - 32][0];

    // ---- gather static weight B-fragments into registers (one-time) ----
    // B: lane l, elem e  <->  B[k = kf*32 + 8*kg + e][n = col], n-tile t = 4g+ub.
    // Same (lane,e)->k map as the A reads below, so any in-octet k permutation
    // cancels in A·B.
    f16x8 bf[2][4][4];   // [ub][gate][kf]; L0 fills kf 0..1 only
    const int NKF = (layer == 0) ? 2 : 4;
#pragma unroll
    for (int ub = 0; ub < 2; ++ub) {
        const int u = 16 * (ubB + ub) + col;
#pragma unroll
        for (int g = 0; g < 4; ++g) {
            for (int kf = 0; kf < NKF; ++kf) {
                f16x8 v;
#pragma unroll
                for (int e = 0; e < 8; ++e) {
                    const int k = kf * 32 + 8 * kg + e;
                    v[e] = (f16)welem(layer, g, u, k,
                                      W_ih0, W_hh0, b0, W_ih1, W_hh1, b1);
                }
                bf[ub][g][kf] = v;
            }
        }
    }

    float cst[2][4] = {{0,0,0,0},{0,0,0,0}};   // cell state, fp32, lane-local
    __syncthreads();

    for (int it = 0; it <= TT; ++it) {
        const int p = it & 1, q = p ^ 1;

        // ===== phase 1: gate matvec via MFMA =====
        // A: lane l, elem e <-> hcat[batch = col][k = kf*32 + 8*kg + e]
        f16x8 a[4];
#pragma unroll
        for (int kf = 0; kf < 4; ++kf)
            a[kf] = *reinterpret_cast<const f16x8*>(&hc[p][col][kf * 32 + 8 * kg]);

        f32x4 acc[2][4];
        const f32x4 z = {0.f, 0.f, 0.f, 0.f};
        if (layer == 0) {
#pragma unroll
            for (int ub = 0; ub < 2; ++ub)
#pragma unroll
                for (int g = 0; g < 4; ++g) {
                    f32x4 c = __builtin_amdgcn_mfma_f32_16x16x32_f16(a[0], bf[ub][g][0], z, 0, 0, 0);
                    c = __builtin_amdgcn_mfma_f32_16x16x32_f16(a[1], bf[ub][g][1], c, 0, 0, 0);
                    acc[ub][g] = c;
                }
        } else {
#pragma unroll
            for (int ub = 0; ub < 2; ++ub)
#pragma unroll
                for (int g = 0; g < 4; ++g) {
                    f32x4 c = __builtin_amdgcn_mfma_f32_16x16x32_f16(a[0], bf[ub][g][0], z, 0, 0, 0);
                    c = __builtin_amdgcn_mfma_f32_16x16x32_f16(a[1], bf[ub][g][1], c, 0, 0, 0);
                    c = __builtin_amdgcn_mfma_f32_16x16x32_f16(a[2], bf[ub][g][2], c, 0, 0, 0);
                    c = __builtin_amdgcn_mfma_f32_16x16x32_f16(a[3], bf[ub][g][3], c, 0, 0, 0);
                    acc[ub][g] = c;
                }
        }

        // ===== phase 2: elementwise (lane-local) + h writes to hc[q] =====
        // D map (HW-verified): D[row = 4*kg + r][col = lane&15]; row = batch.
        const bool ew = (layer == 0) ? (it < TT) : (it >= 1);
        if (ew) {
#pragma unroll
            for (int ub = 0; ub < 2; ++ub) {
                const int u = 16 * (ubB + ub) + col;
#pragma unroll
                for (int r = 0; r < 4; ++r) {
                    const int bat = 4 * kg + r;
                    const float ig = sigm (acc[ub][0][r]);
                    const float fg = sigm (acc[ub][1][r]);
                    const float gg = tanh_(acc[ub][2][r]);
                    const float og = sigm (acc[ub][3][r]);
                    cst[ub][r] = fmaf(fg, cst[ub][r], ig * gg);
                    const float h = og * tanh_(cst[ub][r]);
                    if (u < 50) {   // never clobber x/bias/pad slots
                        hc[q][bat][(layer ? 64 : 0) + u] =
                            __builtin_bit_cast(u16, (f16)h);
                        if (layer == 1 && it == TT) hfin[bat][u] = h;
                    }
                }
            }
        }
        // next step's x into hc[q] slots 50,51 (wave 0, lanes 0..15)
        if (wid == 0 && lane < MB && (it + 1) < TT)
            *reinterpret_cast<u32*>(&hc[q][lane][50]) = xpack[lane][it + 1];

        __syncthreads();
    }

    // ===== final linear head on fp32 h1[T-1] =====
    if (tid < MB) {
        float d = b_fc[0];
#pragma unroll
        for (int u = 0; u < 50; ++u) d = fmaf(W_fc[u], hfin[tid][u], d);
        out[bbase + tid] = d;
    }
}

extern "C" void kernel_launch(void* const* d_in, const int* in_sizes, int n_in,
                              void* d_out, int out_size, void* d_ws, size_t ws_size,
                              hipStream_t stream) {
    const float* x     = (const float*)d_in[0];
    const float* W_ih0 = (const float*)d_in[1];
    const float* W_hh0 = (const float*)d_in[2];
    const float* b0    = (const float*)d_in[3];
    const float* W_ih1 = (const float*)d_in[4];
    const float* W_hh1 = (const float*)d_in[5];
    const float* b1    = (const float*)d_in[6];
    const float* W_fc  = (const float*)d_in[7];
    const float* b_fc  = (const float*)d_in[8];
    float* out = (float*)d_out;

    const int B = in_sizes[0] / (TT * 2);    // 4096
    dim3 grid(B / MB), block(BLK);           // 256 blocks = 1 per CU
    hipLaunchKernelGGL(lstm2_mfma, grid, block, 0, stream,
                       x, W_ih0, W_hh0, b0, W_ih1, W_hh1, b1, W_fc, b_fc, out);
}

// Round 6
// 398.750 us; speedup vs baseline: 7.7725x; 4.8793x over previous
//
#include <hip/hip_runtime.h>

// 2-layer LSTM (H=50) + linear head — MFMA, v2.
//
// Round-5 failure: bf[][][kf] gather loop had a RUNTIME bound (NKF=layer?2:4)
// -> dynamic indexing -> whole fragment array demoted to scratch (VGPR=68,
// WRITE_SIZE 24.6MB of spill traffic, 9120 cyc/step of reload latency at
// 1 wave/SIMD). Fix: constant-bound unrolled fill (L0's extra frags are 0 by
// welem's k-range) + 8-wave block so each SIMD holds 2 waves (1 L0 + 1 L1).
//
// Structure: block = 512 thr (8 waves) owns MB=16 batches; grid = 256 (1/CU).
//   wave w: layer = w>>2, unit-block ub = w&3 (units 16*ub..16*ub+15).
//   Each wave: 4 N-tiles (its 16 units x 4 gates), all gates of a unit in
//   the SAME lane -> elementwise lane-local, cell state in registers.
// K layout per batch (f16): [h0 0..49 | x 50,51 | 1.0 @52 | 0 | h1 64..113 |0]
//   -> bias + x folded into MFMA K-dim. L0: K=64 (2 mfma/gate), L1: K=128 (4).
// Weights = static B-fragments in registers (16 f16x8 = 64 VGPR/wave).
// Double-buffered hc, 1 barrier/step. L1 lags L0 by one step.

typedef _Float16 f16;
typedef f16  f16x8 __attribute__((ext_vector_type(8)));
typedef float f32x4 __attribute__((ext_vector_type(4)));
typedef unsigned short u16;
typedef unsigned int   u32;

#define TT   512
#define MB   16     // batches per block (= MFMA M)
#define KP   136    // hc row length in f16 (128 + 8 pad)
#define XTP  513    // xpack row pad: breaks 16-way bank alias on column reads
#define BLK  512

__device__ __forceinline__ float sigm(float x) {
    return __builtin_amdgcn_rcpf(1.0f + __expf(-x));
}
__device__ __forceinline__ float tanh_(float x) {
    // 1 - 2/(e^{2x}+1); overflow -> inf -> rcp -> 0 -> 1 (correct limit)
    return 1.0f - 2.0f * __builtin_amdgcn_rcpf(__expf(2.0f * x) + 1.0f);
}

// Weight element for B-fragment position (layer, gate g, out-unit u, k).
__device__ __forceinline__ float welem(int layer, int g, int u, int k,
        const float* __restrict__ Wih0, const float* __restrict__ Whh0,
        const float* __restrict__ b0,
        const float* __restrict__ Wih1, const float* __restrict__ Whh1,
        const float* __restrict__ b1) {
    if (u >= 50) return 0.0f;
    const int row = g * 50 + u;           // PyTorch gate order i,f,g,o
    if (layer == 0) {
        if (k < 50)  return Whh0[row * 50 + k];
        if (k < 52)  return Wih0[row * 2 + (k - 50)];
        if (k == 52) return b0[row];
        return 0.0f;                      // k>=53: zero (incl. kf=2,3 frags)
    } else {
        if (k < 50)             return Wih1[row * 50 + k];
        if (k == 52)            return b1[row];
        if (k >= 64 && k < 114) return Whh1[row * 50 + (k - 64)];
        return 0.0f;
    }
}

extern "C" __global__ void __launch_bounds__(BLK, 2)
lstm2_mfma8(const float* __restrict__ x,
            const float* __restrict__ W_ih0, const float* __restrict__ W_hh0,
            const float* __restrict__ b0,
            const float* __restrict__ W_ih1, const float* __restrict__ W_hh1,
            const float* __restrict__ b1,
            const float* __restrict__ W_fc,  const float* __restrict__ b_fc,
            float* __restrict__ out)
{
    __shared__ __align__(16) u16 hc[2][MB][KP];   // 8.7 KB double-buffered state
    __shared__ u32  xpack[MB][XTP];               // 32.8 KB, x as packed f16 pairs
    __shared__ float hfin[MB][52];                // final h1 (fp32) for the head

    const int tid   = threadIdx.x;
    const int lane  = tid & 63;
    const int wid   = tid >> 6;        // 0..7
    const int layer = wid >> 2;        // waves 0-3: L0, waves 4-7: L1
    const int ub    = wid & 3;         // unit-block (16 units)
    const int col   = lane & 15;       // A-row (batch) / B-col (unit) / D-col
    const int kg    = lane >> 4;       // k-octet / D-row group
    const int bbase = blockIdx.x * MB;

    // ---- stage x -> packed f16 pairs in LDS (coalesced float2 loads) ----
    for (int idx = tid; idx < MB * TT; idx += BLK) {
        const int b = idx >> 9, t = idx & (TT - 1);
        const float2 v = *reinterpret_cast<const float2*>(
            x + ((size_t)(bbase + b) * TT + t) * 2);
        xpack[b][t] = (u32)__builtin_bit_cast(u16, (f16)v.x)
                    | ((u32)__builtin_bit_cast(u16, (f16)v.y) << 16);
    }
    // ---- zero hc (both buffers; pads stay 0 forever) ----
    {
        u32* hcU = reinterpret_cast<u32*>(&hc[0][0][0]);
        for (int i = tid; i < 2 * MB * KP / 2; i += BLK) hcU[i] = 0;
    }
    __syncthreads();
    // bias slot (k=52) = f16 1.0 in both buffers; x[0] into buffer 0
    if (tid < 32) hc[tid >> 4][tid & 15][52] = (u16)0x3C00;
    else if (tid < 48)
        *reinterpret_cast<u32*>(&hc[0][tid - 32][50]) = xpack[tid - 32][0];

    // ---- static weight B-fragments (ALL loops constant-bound -> registers) ----
    // B map: lane l, elem e <-> B[k = kf*32 + 8*kg + e][n = col]; same
    // (lane,e)->k map as the A reads below, so in-octet permutations cancel.
    const int u = 16 * ub + col;
    f16x8 bf[4][4];    // [gate][kf]; L0 kf=2,3 are all-zero (harmless, unused)
#pragma unroll
    for (int g = 0; g < 4; ++g) {
#pragma unroll
        for (int kf = 0; kf < 4; ++kf) {
            f16x8 v;
#pragma unroll
            for (int e = 0; e < 8; ++e)
                v[e] = (f16)welem(layer, g, u, kf * 32 + 8 * kg + e,
                                  W_ih0, W_hh0, b0, W_ih1, W_hh1, b1);
            bf[g][kf] = v;
        }
    }

    float cst[4] = {0.f, 0.f, 0.f, 0.f};   // cell state, fp32, lane-local
    __syncthreads();

    for (int it = 0; it <= TT; ++it) {
        const int p = it & 1, q = p ^ 1;

        // ===== phase 1: gates via MFMA =====
        // A map: lane l, elem e <-> hc[p][batch = col][k = kf*32 + 8*kg + e]
        f16x8 a[4];
#pragma unroll
        for (int kf = 0; kf < 4; ++kf)
            a[kf] = *reinterpret_cast<const f16x8*>(&hc[p][col][kf * 32 + 8 * kg]);

        f32x4 acc[4];
        const f32x4 z = {0.f, 0.f, 0.f, 0.f};
        if (layer == 0) {
#pragma unroll
            for (int g = 0; g < 4; ++g) {
                f32x4 c = __builtin_amdgcn_mfma_f32_16x16x32_f16(a[0], bf[g][0], z, 0, 0, 0);
                acc[g]  = __builtin_amdgcn_mfma_f32_16x16x32_f16(a[1], bf[g][1], c, 0, 0, 0);
            }
        } else {
#pragma unroll
            for (int g = 0; g < 4; ++g) {
                f32x4 c = __builtin_amdgcn_mfma_f32_16x16x32_f16(a[0], bf[g][0], z, 0, 0, 0);
                c       = __builtin_amdgcn_mfma_f32_16x16x32_f16(a[1], bf[g][1], c, 0, 0, 0);
                c       = __builtin_amdgcn_mfma_f32_16x16x32_f16(a[2], bf[g][2], c, 0, 0, 0);
                acc[g]  = __builtin_amdgcn_mfma_f32_16x16x32_f16(a[3], bf[g][3], c, 0, 0, 0);
            }
        }

        // ===== phase 2: elementwise (lane-local) + h write to hc[q] =====
        // D map (HW-verified): D[row = 4*kg + r][col]; row = batch, col = unit.
        const bool ew = (layer == 0) ? (it < TT) : (it >= 1);
        if (ew && u < 50) {
#pragma unroll
            for (int r = 0; r < 4; ++r) {
                const int bat = 4 * kg + r;
                const float ig = sigm (acc[0][r]);
                const float fg = sigm (acc[1][r]);
                const float gg = tanh_(acc[2][r]);
                const float og = sigm (acc[3][r]);
                cst[r] = fmaf(fg, cst[r], ig * gg);
                const float h = og * tanh_(cst[r]);
                hc[q][bat][(layer ? 64 : 0) + u] = __builtin_bit_cast(u16, (f16)h);
                if (layer == 1 && it == TT) hfin[bat][u] = h;
            }
        }
        // next step's x into hc[q] slots 50,51
        if (wid == 0 && lane < MB && (it + 1) < TT)
            *reinterpret_cast<u32*>(&hc[q][lane][50]) = xpack[lane][it + 1];

        __syncthreads();
    }

    // ===== final linear head on fp32 h1[T-1] =====
    if (tid < MB) {
        float d = b_fc[0];
#pragma unroll
        for (int uu = 0; uu < 50; ++uu) d = fmaf(W_fc[uu], hfin[tid][uu], d);
        out[bbase + tid] = d;
    }
}

extern "C" void kernel_launch(void* const* d_in, const int* in_sizes, int n_in,
                              void* d_out, int out_size, void* d_ws, size_t ws_size,
                              hipStream_t stream) {
    const float* x     = (const float*)d_in[0];
    const float* W_ih0 = (const float*)d_in[1];
    const float* W_hh0 = (const float*)d_in[2];
    const float* b0    = (const float*)d_in[3];
    const float* W_ih1 = (const float*)d_in[4];
    const float* W_hh1 = (const float*)d_in[5];
    const float* b1    = (const float*)d_in[6];
    const float* W_fc  = (const float*)d_in[7];
    const float* b_fc  = (const float*)d_in[8];
    float* out = (float*)d_out;

    const int B = in_sizes[0] / (TT * 2);    // 4096
    dim3 grid(B / MB), block(BLK);           // 256 blocks = 1 per CU
    hipLaunchKernelGGL(lstm2_mfma8, grid, block, 0, stream,
                       x, W_ih0, W_hh0, b0, W_ih1, W_hh1, b1, W_fc, b_fc, out);
}